// Round 4
// baseline (1358.486 us; speedup 1.0000x reference)
//
#include <hip/hip_runtime.h>
#include <stdint.h>
#include <math.h>

#define N_TOK 4096
#define H_DIM 4096
#define V_DIM 32000

// ---- 8-phase 256x256 GEMM geometry ----
#define BM2 256
#define BN2 256
#define BK2 64
#define NKT (H_DIM / BK2)     // 64 K-tiles
#define CT2 (V_DIM / BN2)     // 125 column tiles
#define MT2 (N_TOK / BM2)     // 16 row tiles

// ---- legacy 128x128 fallback geometry (small-ws) ----
#define BM 128
#define BN 128
#define BK 64
#define CT_NUM (V_DIM / BN)   // 250
#define MT_NUM (N_TOK / BM)   // 32

typedef __attribute__((ext_vector_type(8))) short short8;
typedef __attribute__((ext_vector_type(4))) float f32x4;
typedef __attribute__((ext_vector_type(16))) float f32x16;

#define MFMA32(a, b, c) __builtin_amdgcn_mfma_f32_32x32x16_bf16(a, b, c, 0, 0, 0)
#define BARRIER() asm volatile("s_barrier" ::: "memory")
#define LGKM0() asm volatile("s_waitcnt lgkmcnt(0)" ::: "memory")

__device__ __forceinline__ unsigned short f2bf(float x) {
  union { float f; unsigned int u; } v; v.f = x;
  unsigned int r = v.u + 0x7fffu + ((v.u >> 16) & 1u);
  return (unsigned short)(r >> 16);
}

__device__ __forceinline__ void async16(const unsigned short* g, void* lds) {
  __builtin_amdgcn_global_load_lds(
      (const __attribute__((address_space(1))) void*)g,
      (__attribute__((address_space(3))) void*)lds, 16, 0, 0);
}

__global__ __launch_bounds__(256) void cast_f32_to_bf16(
    const float* __restrict__ in, unsigned short* __restrict__ out, int n4) {
  int stride = gridDim.x * blockDim.x;
  for (int idx = blockIdx.x * blockDim.x + threadIdx.x; idx < n4; idx += stride) {
    float4 v = ((const float4*)in)[idx];
    ushort4 o;
    o.x = f2bf(v.x); o.y = f2bf(v.y); o.z = f2bf(v.z); o.w = f2bf(v.w);
    ((ushort4*)out)[idx] = o;
  }
}

// Stage one 64-row x 64-col bf16 chunk (8 KB) with 512 threads (1 instr each).
// Logical 16B-slot q of row r lands at physical slot q ^ (r&7): linear LDS
// dest (global_load_lds requirement) + inverse-permuted global source.
__device__ __forceinline__ void stage_chunk(const unsigned short* __restrict__ src,
                                            int grow0, int kt, char* dest, int tid) {
  const int ls = (tid & 7) ^ ((tid >> 3) & 7);
  const unsigned short* g = src + (size_t)(grow0 + (tid >> 3)) * H_DIM + kt * 64 + ls * 8;
  async16(g, dest + (tid >> 6) * 1024);
}

// One K-tile (4 phases) of the 8-phase schedule. Tile g is in buf P = g&1.
// Staging: q0/q1 -> A(ktA) into buf^1 (quarters aligned to read phases);
// q2/q3 -> B(ktB = g+2) into CURRENT buf's B region (its tile-g data was
// register-captured at q0/q1). vmcnt invariant (instr units), entering group:
// outstanding = {aOdd(g)[2], B(g+1)[4]}. q1: +aE(g+1)+aO(g+1) -> 10,
// vmcnt(8) drains aOdd(g) (needed q2, issued 4 phases ago). q3: +B(g+2) ->
// 12, vmcnt(6) drains B(g+1)+aEven(g+1) (3-5 phases old) -> invariant holds.
template<int P>
__device__ __forceinline__ void phase_group(char* lds,
    const unsigned short* __restrict__ Xb, const unsigned short* __restrict__ Wb,
    int mbase, int cbase, int ktA, int ktB, int tid,
    const int (&aOff)[4], const int (&bOff)[2], const int (&slot16)[4],
    f32x16 (&acc)[4][2]) {
  char* aB = lds + P * 65536;
  char* bB = aB + 32768;
  char* aN = lds + (P ^ 1) * 65536;
  short8 breg[2][4];   // [cf][ks], loaded ks01 at q0, ks23 at q1
  short8 ar[2][2];     // [rf-in-pair][ks-in-pair]

  // ---- q0: rf01 x ks01 ----
  stage_chunk(Xb, mbase + 0,   ktA, aN + 0,     tid);
  stage_chunk(Xb, mbase + 128, ktA, aN + 16384, tid);
  breg[0][0] = *(const short8*)(bB + bOff[0] + slot16[0]);
  breg[0][1] = *(const short8*)(bB + bOff[0] + slot16[1]);
  breg[1][0] = *(const short8*)(bB + bOff[1] + slot16[0]);
  breg[1][1] = *(const short8*)(bB + bOff[1] + slot16[1]);
  ar[0][0] = *(const short8*)(aB + aOff[0] + slot16[0]);
  ar[0][1] = *(const short8*)(aB + aOff[0] + slot16[1]);
  ar[1][0] = *(const short8*)(aB + aOff[1] + slot16[0]);
  ar[1][1] = *(const short8*)(aB + aOff[1] + slot16[1]);
  BARRIER();
  __builtin_amdgcn_s_setprio(1);
  acc[0][0] = MFMA32(ar[0][0], breg[0][0], acc[0][0]);
  acc[0][1] = MFMA32(ar[0][0], breg[1][0], acc[0][1]);
  acc[1][0] = MFMA32(ar[1][0], breg[0][0], acc[1][0]);
  acc[1][1] = MFMA32(ar[1][0], breg[1][0], acc[1][1]);
  acc[0][0] = MFMA32(ar[0][1], breg[0][1], acc[0][0]);
  acc[0][1] = MFMA32(ar[0][1], breg[1][1], acc[0][1]);
  acc[1][0] = MFMA32(ar[1][1], breg[0][1], acc[1][0]);
  acc[1][1] = MFMA32(ar[1][1], breg[1][1], acc[1][1]);
  __builtin_amdgcn_s_setprio(0);
  LGKM0();
  BARRIER();

  // ---- q1: rf01 x ks23 ----
  stage_chunk(Xb, mbase + 64,  ktA, aN + 8192,  tid);
  stage_chunk(Xb, mbase + 192, ktA, aN + 24576, tid);
  breg[0][2] = *(const short8*)(bB + bOff[0] + slot16[2]);
  breg[0][3] = *(const short8*)(bB + bOff[0] + slot16[3]);
  breg[1][2] = *(const short8*)(bB + bOff[1] + slot16[2]);
  breg[1][3] = *(const short8*)(bB + bOff[1] + slot16[3]);
  ar[0][0] = *(const short8*)(aB + aOff[0] + slot16[2]);
  ar[0][1] = *(const short8*)(aB + aOff[0] + slot16[3]);
  ar[1][0] = *(const short8*)(aB + aOff[1] + slot16[2]);
  ar[1][1] = *(const short8*)(aB + aOff[1] + slot16[3]);
  asm volatile("s_waitcnt vmcnt(8)" ::: "memory");
  BARRIER();
  __builtin_amdgcn_s_setprio(1);
  acc[0][0] = MFMA32(ar[0][0], breg[0][2], acc[0][0]);
  acc[0][1] = MFMA32(ar[0][0], breg[1][2], acc[0][1]);
  acc[1][0] = MFMA32(ar[1][0], breg[0][2], acc[1][0]);
  acc[1][1] = MFMA32(ar[1][0], breg[1][2], acc[1][1]);
  acc[0][0] = MFMA32(ar[0][1], breg[0][3], acc[0][0]);
  acc[0][1] = MFMA32(ar[0][1], breg[1][3], acc[0][1]);
  acc[1][0] = MFMA32(ar[1][1], breg[0][3], acc[1][0]);
  acc[1][1] = MFMA32(ar[1][1], breg[1][3], acc[1][1]);
  __builtin_amdgcn_s_setprio(0);
  LGKM0();
  BARRIER();

  // ---- q2: rf23 x ks01 ----
  stage_chunk(Wb, cbase + 0,  ktB, bB + 0,    tid);
  stage_chunk(Wb, cbase + 64, ktB, bB + 8192, tid);
  ar[0][0] = *(const short8*)(aB + aOff[2] + slot16[0]);
  ar[0][1] = *(const short8*)(aB + aOff[2] + slot16[1]);
  ar[1][0] = *(const short8*)(aB + aOff[3] + slot16[0]);
  ar[1][1] = *(const short8*)(aB + aOff[3] + slot16[1]);
  BARRIER();
  __builtin_amdgcn_s_setprio(1);
  acc[2][0] = MFMA32(ar[0][0], breg[0][0], acc[2][0]);
  acc[2][1] = MFMA32(ar[0][0], breg[1][0], acc[2][1]);
  acc[3][0] = MFMA32(ar[1][0], breg[0][0], acc[3][0]);
  acc[3][1] = MFMA32(ar[1][0], breg[1][0], acc[3][1]);
  acc[2][0] = MFMA32(ar[0][1], breg[0][1], acc[2][0]);
  acc[2][1] = MFMA32(ar[0][1], breg[1][1], acc[2][1]);
  acc[3][0] = MFMA32(ar[1][1], breg[0][1], acc[3][0]);
  acc[3][1] = MFMA32(ar[1][1], breg[1][1], acc[3][1]);
  __builtin_amdgcn_s_setprio(0);
  LGKM0();
  BARRIER();

  // ---- q3: rf23 x ks23 ----
  stage_chunk(Wb, cbase + 128, ktB, bB + 16384, tid);
  stage_chunk(Wb, cbase + 192, ktB, bB + 24576, tid);
  ar[0][0] = *(const short8*)(aB + aOff[2] + slot16[2]);
  ar[0][1] = *(const short8*)(aB + aOff[2] + slot16[3]);
  ar[1][0] = *(const short8*)(aB + aOff[3] + slot16[2]);
  ar[1][1] = *(const short8*)(aB + aOff[3] + slot16[3]);
  asm volatile("s_waitcnt vmcnt(6)" ::: "memory");
  BARRIER();
  __builtin_amdgcn_s_setprio(1);
  acc[2][0] = MFMA32(ar[0][0], breg[0][2], acc[2][0]);
  acc[2][1] = MFMA32(ar[0][0], breg[1][2], acc[2][1]);
  acc[3][0] = MFMA32(ar[1][0], breg[0][2], acc[3][0]);
  acc[3][1] = MFMA32(ar[1][0], breg[1][2], acc[3][1]);
  acc[2][0] = MFMA32(ar[0][1], breg[0][3], acc[2][0]);
  acc[2][1] = MFMA32(ar[0][1], breg[1][3], acc[2][1]);
  acc[3][0] = MFMA32(ar[1][1], breg[0][3], acc[3][0]);
  acc[3][1] = MFMA32(ar[1][1], breg[1][3], acc[3][1]);
  __builtin_amdgcn_s_setprio(0);
  LGKM0();
  BARRIER();
}

__global__ __launch_bounds__(512, 2) void gemm_lse8(
    const unsigned short* __restrict__ Xb, const unsigned short* __restrict__ Wb,
    float* __restrict__ pmax, float* __restrict__ psum) {
  extern __shared__ char lds[];
  const int tid = threadIdx.x;
  const int lane = tid & 63;
  const int wid = tid >> 6;
  const int wm = wid >> 2, wn = wid & 3;

  // XCD-aware swizzle (2000 % 8 == 0 -> bijective), mt-fastest for W reuse.
  int logical = (blockIdx.x & 7) * (CT2 * MT2 / 8) + (blockIdx.x >> 3);
  const int ct = logical / MT2, mt = logical - ct * MT2;
  const int mbase = mt * BM2, cbase = ct * BN2;

  const int l31 = lane & 31;
  const int khalf = lane >> 5;
  const int swz = lane & 7;
  int slot16[4], aOff[4], bOff[2];
#pragma unroll
  for (int ks = 0; ks < 4; ks++) slot16[ks] = ((ks * 2 + khalf) ^ swz) << 4;
#pragma unroll
  for (int rf = 0; rf < 4; rf++) aOff[rf] = (wm * 128 + rf * 32 + l31) * 128;
#pragma unroll
  for (int cf = 0; cf < 2; cf++) bOff[cf] = (wn * 64 + cf * 32 + l31) * 128;

  f32x16 acc[4][2];
#pragma unroll
  for (int i = 0; i < 4; i++)
#pragma unroll
    for (int j = 0; j < 2; j++)
#pragma unroll
      for (int r = 0; r < 16; r++) acc[i][j][r] = 0.f;

  // Prologue. Issue order matters for the vmcnt invariant:
  // B(0)[4], aEven(0)[2], aOdd(0)[2], B(1)[4]; vmcnt(6) keeps
  // {aOdd(0)(oldest), B(1)} outstanding = steady-state invariant.
  {
    char* b0 = lds + 32768;
    char* b1 = lds + 65536 + 32768;
    stage_chunk(Wb, cbase + 0,   0, b0 + 0,     tid);
    stage_chunk(Wb, cbase + 64,  0, b0 + 8192,  tid);
    stage_chunk(Wb, cbase + 128, 0, b0 + 16384, tid);
    stage_chunk(Wb, cbase + 192, 0, b0 + 24576, tid);
    stage_chunk(Xb, mbase + 0,   0, lds + 0,     tid);
    stage_chunk(Xb, mbase + 128, 0, lds + 16384, tid);
    stage_chunk(Xb, mbase + 64,  0, lds + 8192,  tid);
    stage_chunk(Xb, mbase + 192, 0, lds + 24576, tid);
    stage_chunk(Wb, cbase + 0,   1, b1 + 0,     tid);
    stage_chunk(Wb, cbase + 64,  1, b1 + 8192,  tid);
    stage_chunk(Wb, cbase + 128, 1, b1 + 16384, tid);
    stage_chunk(Wb, cbase + 192, 1, b1 + 24576, tid);
    asm volatile("s_waitcnt vmcnt(6)" ::: "memory");
    BARRIER();
  }

#pragma unroll 1
  for (int i = 0; i < NKT / 2; i++) {
    int g0 = 2 * i, g1 = 2 * i + 1;
    int b0t = (g0 + 2 < NKT) ? g0 + 2 : NKT - 1;
    int a1t = (g1 + 1 < NKT) ? g1 + 1 : NKT - 1;
    int b1t = (g1 + 2 < NKT) ? g1 + 2 : NKT - 1;
    phase_group<0>(lds, Xb, Wb, mbase, cbase, g0 + 1, b0t, tid,
                   aOff, bOff, slot16, acc);
    phase_group<1>(lds, Xb, Wb, mbase, cbase, a1t, b1t, tid,
                   aOff, bOff, slot16, acc);
  }

  asm volatile("s_waitcnt vmcnt(0)" ::: "memory");
  __syncthreads();

  // Per-row (max, sum-exp) over this block's 256 vocab columns.
  // 32x32 C/D map: col = lane&31, row = (r&3) + 8*(r>>2) + 4*(lane>>5).
  float2* red = (float2*)lds;   // [256 rows][4 wn]
#pragma unroll
  for (int rf = 0; rf < 4; rf++) {
#pragma unroll
    for (int r = 0; r < 16; r++) {
      float v0 = acc[rf][0][r], v1 = acc[rf][1][r];
      float mx = fmaxf(v0, v1);
#pragma unroll
      for (int d = 1; d < 32; d <<= 1) mx = fmaxf(mx, __shfl_xor(mx, d));
      float se = __expf(v0 - mx) + __expf(v1 - mx);
#pragma unroll
      for (int d = 1; d < 32; d <<= 1) se += __shfl_xor(se, d);
      if (l31 == 0) {
        int row = wm * 128 + rf * 32 + (r & 3) + 8 * (r >> 2) + 4 * khalf;
        float2 v; v.x = mx; v.y = se;
        red[row * 4 + wn] = v;
      }
    }
  }
  __syncthreads();
  if (tid < 256) {
    float M = -INFINITY, S = 0.f;
#pragma unroll
    for (int w = 0; w < 4; w++) {
      float2 rr = red[tid * 4 + w];
      float Mn = fmaxf(M, rr.x);
      S = S * __expf(M - Mn) + rr.y * __expf(rr.x - Mn);
      M = Mn;
    }
    size_t o = (size_t)ct * N_TOK + mbase + tid;
    pmax[o] = M;
    psum[o] = S;
  }
}

// ---------------- legacy 128^2 kernel, small-ws fallback (fp32 inputs) ------
__global__ __launch_bounds__(256) void gemm_lse_small(
    const float* __restrict__ Xf, const float* __restrict__ Wf,
    float* __restrict__ pmax, float* __restrict__ psum) {
  __shared__ unsigned short As[BM * BK];
  __shared__ unsigned short Bs[BN * BK];
  const int ct = blockIdx.x / MT_NUM;
  const int mt = blockIdx.x % MT_NUM;
  const int mbase = mt * BM, cbase = ct * BN;
  const int tid = threadIdx.x;
  const int lane = tid & 63;
  const int wid = tid >> 6;
  const int wr = wid >> 1, wc = wid & 1;
  f32x4 acc[4][4];
#pragma unroll
  for (int i = 0; i < 4; i++)
#pragma unroll
    for (int j = 0; j < 4; j++) { f32x4 z = {0.f, 0.f, 0.f, 0.f}; acc[i][j] = z; }
  for (int ks = 0; ks < H_DIM / BK; ks++) {
    const int k0 = ks * BK;
#pragma unroll
    for (int r = 0; r < 4; r++) {
      int o = r * 4096 + wid * 1024 + lane * 16;
      int row = o >> 7;
      int kc = (o & 127) >> 1;
      const float* xs = Xf + (size_t)(mbase + row) * H_DIM + k0 + kc;
      const float* wv = Wf + (size_t)(cbase + row) * H_DIM + k0 + kc;
      float4 x0 = *(const float4*)xs, x1 = *(const float4*)(xs + 4);
      float4 w0 = *(const float4*)wv, w1 = *(const float4*)(wv + 4);
      short8 xa, wa;
      xa[0] = f2bf(x0.x); xa[1] = f2bf(x0.y); xa[2] = f2bf(x0.z); xa[3] = f2bf(x0.w);
      xa[4] = f2bf(x1.x); xa[5] = f2bf(x1.y); xa[6] = f2bf(x1.z); xa[7] = f2bf(x1.w);
      wa[0] = f2bf(w0.x); wa[1] = f2bf(w0.y); wa[2] = f2bf(w0.z); wa[3] = f2bf(w0.w);
      wa[4] = f2bf(w1.x); wa[5] = f2bf(w1.y); wa[6] = f2bf(w1.z); wa[7] = f2bf(w1.w);
      *(short8*)((char*)As + o) = xa;
      *(short8*)((char*)Bs + o) = wa;
    }
    __syncthreads();
#pragma unroll
    for (int kk = 0; kk < 2; kk++) {
      short8 a[4], b[4];
#pragma unroll
      for (int m = 0; m < 4; m++)
        a[m] = *(const short8*)((const char*)As +
                (wr * 64 + m * 16 + (lane & 15)) * 128 + kk * 64 + (lane >> 4) * 16);
#pragma unroll
      for (int n = 0; n < 4; n++)
        b[n] = *(const short8*)((const char*)Bs +
                (wc * 64 + n * 16 + (lane & 15)) * 128 + kk * 64 + (lane >> 4) * 16);
#pragma unroll
      for (int m = 0; m < 4; m++)
#pragma unroll
        for (int n = 0; n < 4; n++)
          acc[m][n] = __builtin_amdgcn_mfma_f32_16x16x32_bf16(a[m], b[n], acc[m][n], 0, 0, 0);
    }
    __syncthreads();
  }
  float* red = (float*)As;
  const int g = lane >> 4;
#pragma unroll
  for (int m = 0; m < 4; m++) {
#pragma unroll
    for (int q = 0; q < 4; q++) {
      float v0 = acc[m][0][q], v1 = acc[m][1][q], v2 = acc[m][2][q], v3 = acc[m][3][q];
      float mx = fmaxf(fmaxf(v0, v1), fmaxf(v2, v3));
#pragma unroll
      for (int d = 1; d < 16; d <<= 1) mx = fmaxf(mx, __shfl_xor(mx, d));
      float se = __expf(v0 - mx) + __expf(v1 - mx) + __expf(v2 - mx) + __expf(v3 - mx);
#pragma unroll
      for (int d = 1; d < 16; d <<= 1) se += __shfl_xor(se, d);
      if ((lane & 15) == 0) {
        int row = wr * 64 + m * 16 + g * 4 + q;
        red[row * 4 + wc * 2 + 0] = mx;
        red[row * 4 + wc * 2 + 1] = se;
      }
    }
  }
  __syncthreads();
  if (tid < BM) {
    float m0 = red[tid * 4 + 0], s0 = red[tid * 4 + 1];
    float m1 = red[tid * 4 + 2], s1 = red[tid * 4 + 3];
    float M = fmaxf(m0, m1);
    float S = s0 * __expf(m0 - M) + s1 * __expf(m1 - M);
    size_t o = (size_t)ct * N_TOK + mbase + tid;
    pmax[o] = M;
    psum[o] = S;
  }
}

// ---------------- exact fp32 target logit + reduction kernels ---------------
__global__ __launch_bounds__(256) void target_logit(
    const float* __restrict__ X, const float* __restrict__ W,
    const int* __restrict__ y, float* __restrict__ tl) {
  __shared__ float red[4];
  int row = blockIdx.x;
  int lab = y[row];
  float s = 0.f;
  if (lab >= 0 && lab < V_DIM) {
    const float4* xr = (const float4*)(X + (size_t)row * H_DIM);
    const float4* wr = (const float4*)(W + (size_t)lab * H_DIM);
    for (int i = threadIdx.x; i < H_DIM / 4; i += 256) {
      float4 a = xr[i], b = wr[i];
      s += a.x * b.x + a.y * b.y + a.z * b.z + a.w * b.w;
    }
  }
#pragma unroll
  for (int o = 32; o > 0; o >>= 1) s += __shfl_down(s, o);
  if ((threadIdx.x & 63) == 0) red[threadIdx.x >> 6] = s;
  __syncthreads();
  if (threadIdx.x == 0) tl[row] = red[0] + red[1] + red[2] + red[3];
}

__global__ __launch_bounds__(256) void combine_rows(
    const float* __restrict__ pmax, const float* __restrict__ psum,
    const float* __restrict__ tl, const int* __restrict__ y,
    float* __restrict__ lossb, float* __restrict__ validb, int n_ct) {
  int row = blockIdx.x * 256 + threadIdx.x;
  if (row >= N_TOK) return;
  float M = -INFINITY, S = 0.f;
  for (int ct = 0; ct < n_ct; ct++) {
    float m = pmax[(size_t)ct * N_TOK + row];
    float s = psum[(size_t)ct * N_TOK + row];
    float Mn = fmaxf(M, m);
    S = S * __expf(M - Mn) + s * __expf(m - Mn);
    M = Mn;
  }
  bool valid = (y[row] != -100);
  lossb[row] = valid ? (M + __logf(S) - tl[row]) : 0.f;
  validb[row] = valid ? 1.f : 0.f;
}

__global__ __launch_bounds__(256) void finalize_loss(
    const float* __restrict__ lossb, const float* __restrict__ validb,
    float* __restrict__ out) {
  __shared__ float rs[4], rc[4];
  float s = 0.f, c = 0.f;
  for (int i = threadIdx.x; i < N_TOK; i += 256) { s += lossb[i]; c += validb[i]; }
#pragma unroll
  for (int o = 32; o > 0; o >>= 1) { s += __shfl_down(s, o); c += __shfl_down(c, o); }
  if ((threadIdx.x & 63) == 0) { rs[threadIdx.x >> 6] = s; rc[threadIdx.x >> 6] = c; }
  __syncthreads();
  if (threadIdx.x == 0) {
    float S = rs[0] + rs[1] + rs[2] + rs[3];
    float C = rc[0] + rc[1] + rc[2] + rc[3];
    out[0] = S / fmaxf(C, 1.f);
  }
}

extern "C" void kernel_launch(void* const* d_in, const int* in_sizes, int n_in,
                              void* d_out, int out_size, void* d_ws, size_t ws_size,
                              hipStream_t stream) {
  const float* x = (const float*)d_in[0];
  const int* y = (const int*)d_in[1];
  const float* W = (const float*)d_in[2];
  float* out = (float*)d_out;
  char* ws = (char*)d_ws;

  const size_t szWb = (size_t)V_DIM * H_DIM * 2;
  const size_t szXb = (size_t)N_TOK * H_DIM * 2;
  const size_t szP  = (size_t)CT_NUM * N_TOK * 4;   // sized for 250-tile fallback
  const size_t szT  = (size_t)N_TOK * 4;
  const size_t needFull = szWb + szXb + 2 * szP + 3 * szT;

  bool full = (ws_size >= needFull);
  unsigned short* Wb = nullptr;
  unsigned short* Xb = nullptr;
  size_t off = 0;
  if (full) { Wb = (unsigned short*)ws; Xb = (unsigned short*)(ws + szWb); off = szWb + szXb; }
  float* pmax   = (float*)(ws + off); off += szP;
  float* psum   = (float*)(ws + off); off += szP;
  float* tl     = (float*)(ws + off); off += szT;
  float* lossb  = (float*)(ws + off); off += szT;
  float* validb = (float*)(ws + off);

  if (full) {
    cast_f32_to_bf16<<<4096, 256, 0, stream>>>(W, Wb, (int)((size_t)V_DIM * H_DIM / 4));
    cast_f32_to_bf16<<<1024, 256, 0, stream>>>(x, Xb, (int)((size_t)N_TOK * H_DIM / 4));
    (void)hipFuncSetAttribute((const void*)gemm_lse8,
        hipFuncAttributeMaxDynamicSharedMemorySize, 131072);
    gemm_lse8<<<CT2 * MT2, 512, 131072, stream>>>(Xb, Wb, pmax, psum);
    target_logit<<<N_TOK, 256, 0, stream>>>(x, W, y, tl);
    combine_rows<<<N_TOK / 256, 256, 0, stream>>>(pmax, psum, tl, y, lossb, validb, CT2);
  } else {
    gemm_lse_small<<<CT_NUM * MT_NUM, 256, 0, stream>>>(x, W, pmax, psum);
    target_logit<<<N_TOK, 256, 0, stream>>>(x, W, y, tl);
    combine_rows<<<N_TOK / 256, 256, 0, stream>>>(pmax, psum, tl, y, lossb, validb, CT_NUM);
  }
  finalize_loss<<<1, 256, 0, stream>>>(lossb, validb, out);
}

// Round 5
// 1120.122 us; speedup vs baseline: 1.2128x; 1.2128x over previous
//
#include <hip/hip_runtime.h>
#include <stdint.h>
#include <math.h>

#define N_TOK 4096
#define H_DIM 4096
#define V_DIM 32000

// ---- 8-phase 256x256 GEMM geometry ----
#define BM2 256
#define BN2 256
#define BK2 64
#define NKT (H_DIM / BK2)     // 64 K-tiles
#define CT2 (V_DIM / BN2)     // 125 column tiles
#define MT2 (N_TOK / BM2)     // 16 row tiles

// ---- legacy 128x128 fallback geometry (small-ws) ----
#define BM 128
#define BN 128
#define BK 64
#define CT_NUM (V_DIM / BN)   // 250
#define MT_NUM (N_TOK / BM)   // 32

typedef __attribute__((ext_vector_type(8))) short short8;
typedef __attribute__((ext_vector_type(4))) float f32x4;

#define MFMA16(a, b, c) __builtin_amdgcn_mfma_f32_16x16x32_bf16(a, b, c, 0, 0, 0)
#define BARRIER() asm volatile("s_barrier" ::: "memory")

__device__ __forceinline__ unsigned short f2bf(float x) {
  union { float f; unsigned int u; } v; v.f = x;
  unsigned int r = v.u + 0x7fffu + ((v.u >> 16) & 1u);
  return (unsigned short)(r >> 16);
}

__device__ __forceinline__ void async16(const unsigned short* g, void* lds) {
  __builtin_amdgcn_global_load_lds(
      (const __attribute__((address_space(1))) void*)g,
      (__attribute__((address_space(3))) void*)lds, 16, 0, 0);
}

__global__ __launch_bounds__(256) void cast_f32_to_bf16(
    const float* __restrict__ in, unsigned short* __restrict__ out, int n4) {
  int stride = gridDim.x * blockDim.x;
  for (int idx = blockIdx.x * blockDim.x + threadIdx.x; idx < n4; idx += stride) {
    float4 v = ((const float4*)in)[idx];
    ushort4 o;
    o.x = f2bf(v.x); o.y = f2bf(v.y); o.z = f2bf(v.z); o.w = f2bf(v.w);
    ((ushort4*)out)[idx] = o;
  }
}

// Stage one 64-row x 64-col bf16 chunk (8 KB), 512 threads, 1 instr each.
// Logical 16B-slot s of row r lands at physical slot s ^ (r&7): linear LDS
// dest (global_load_lds requirement) + inverse-permuted global source.
__device__ __forceinline__ void stage_chunk(const unsigned short* __restrict__ src,
                                            int grow0, int kt, char* dest, int tid) {
  const int ls = (tid & 7) ^ ((tid >> 3) & 7);
  const unsigned short* g = src + (size_t)(grow0 + (tid >> 3)) * H_DIM + kt * 64 + ls * 8;
  async16(g, dest + (tid >> 6) * 1024);
}

// 16 MFMA cluster for m-frags MF,MF+1 x all 4 n-frags x kk0/kk1.
// kk-outer order: each acc is reused at dep distance 8.
template<int MF>
__device__ __forceinline__ void cluster16(f32x4 (&acc)[8][4],
    short8 a00, short8 a01, short8 a10, short8 a11, short8 (&breg)[4][2]) {
#pragma unroll
  for (int nf = 0; nf < 4; nf++) acc[MF][nf]     = MFMA16(a00, breg[nf][0], acc[MF][nf]);
#pragma unroll
  for (int nf = 0; nf < 4; nf++) acc[MF + 1][nf] = MFMA16(a10, breg[nf][0], acc[MF + 1][nf]);
#pragma unroll
  for (int nf = 0; nf < 4; nf++) acc[MF][nf]     = MFMA16(a01, breg[nf][1], acc[MF][nf]);
#pragma unroll
  for (int nf = 0; nf < 4; nf++) acc[MF + 1][nf] = MFMA16(a11, breg[nf][1], acc[MF + 1][nf]);
}

// One K-tile (4 phases). Tile g lives in buf P = g&1.
// Stages: q0/q1 -> A(g+1) into buf^1 (q0: ch0,ch2 = rows 0-63,128-191;
// q1: ch1,ch3); q2/q3 -> B(g+2) into CURRENT buf's B region (tile-g B was
// register-captured into breg at q0). vmcnt FIFO invariant (instr units),
// entering q0: outstanding = {A(g)ch13 x2, B(g+1) x4} = 6.
//   q0 +2 -> 8; q1 +2 -> 10, vmcnt(8) drains A(g)ch13 (needed q2, 5-phase-old)
//   q2 +2 -> 10; q3 +2 -> 12, vmcnt(6) drains B(g+1)x4 + A(g+1)ch02
//   (needed next q0; 3..6-phase slack) -> invariant restored.
template<int P>
__device__ __forceinline__ void phase_group(char* lds,
    const unsigned short* __restrict__ Xb, const unsigned short* __restrict__ Wb,
    int mbase, int cbase, int ktA, int ktB, int tid,
    int aRowByte, int bRowByte, int c0, int c1, f32x4 (&acc)[8][4]) {
  const char* aB = lds + P * 65536;
  const char* bB = aB + 32768;
  char* aN = lds + (P ^ 1) * 65536;
  char* bC = lds + P * 65536 + 32768;
  short8 breg[4][2];

  // ---- q0: frags 0,1 ----
  stage_chunk(Xb, mbase + 0,   ktA, aN + 0,     tid);
  stage_chunk(Xb, mbase + 128, ktA, aN + 16384, tid);
#pragma unroll
  for (int nf = 0; nf < 4; nf++) {
    breg[nf][0] = *(const short8*)(bB + bRowByte + nf * 2048 + c0);
    breg[nf][1] = *(const short8*)(bB + bRowByte + nf * 2048 + c1);
  }
  {
    short8 a00 = *(const short8*)(aB + aRowByte + 0 * 2048 + c0);
    short8 a01 = *(const short8*)(aB + aRowByte + 0 * 2048 + c1);
    short8 a10 = *(const short8*)(aB + aRowByte + 1 * 2048 + c0);
    short8 a11 = *(const short8*)(aB + aRowByte + 1 * 2048 + c1);
    BARRIER();
    __builtin_amdgcn_s_setprio(1);
    cluster16<0>(acc, a00, a01, a10, a11, breg);
    __builtin_amdgcn_s_setprio(0);
    BARRIER();
  }
  // ---- q1: frags 2,3 ----
  stage_chunk(Xb, mbase + 64,  ktA, aN + 8192,  tid);
  stage_chunk(Xb, mbase + 192, ktA, aN + 24576, tid);
  {
    short8 a00 = *(const short8*)(aB + aRowByte + 2 * 2048 + c0);
    short8 a01 = *(const short8*)(aB + aRowByte + 2 * 2048 + c1);
    short8 a10 = *(const short8*)(aB + aRowByte + 3 * 2048 + c0);
    short8 a11 = *(const short8*)(aB + aRowByte + 3 * 2048 + c1);
    asm volatile("s_waitcnt vmcnt(8)" ::: "memory");
    BARRIER();
    __builtin_amdgcn_s_setprio(1);
    cluster16<2>(acc, a00, a01, a10, a11, breg);
    __builtin_amdgcn_s_setprio(0);
    BARRIER();
  }
  // ---- q2: frags 4,5 ----
  stage_chunk(Wb, cbase + 0,  ktB, bC + 0,    tid);
  stage_chunk(Wb, cbase + 64, ktB, bC + 8192, tid);
  {
    short8 a00 = *(const short8*)(aB + aRowByte + 4 * 2048 + c0);
    short8 a01 = *(const short8*)(aB + aRowByte + 4 * 2048 + c1);
    short8 a10 = *(const short8*)(aB + aRowByte + 5 * 2048 + c0);
    short8 a11 = *(const short8*)(aB + aRowByte + 5 * 2048 + c1);
    BARRIER();
    __builtin_amdgcn_s_setprio(1);
    cluster16<4>(acc, a00, a01, a10, a11, breg);
    __builtin_amdgcn_s_setprio(0);
    BARRIER();
  }
  // ---- q3: frags 6,7 ----
  stage_chunk(Wb, cbase + 128, ktB, bC + 16384, tid);
  stage_chunk(Wb, cbase + 192, ktB, bC + 24576, tid);
  {
    short8 a00 = *(const short8*)(aB + aRowByte + 6 * 2048 + c0);
    short8 a01 = *(const short8*)(aB + aRowByte + 6 * 2048 + c1);
    short8 a10 = *(const short8*)(aB + aRowByte + 7 * 2048 + c0);
    short8 a11 = *(const short8*)(aB + aRowByte + 7 * 2048 + c1);
    asm volatile("s_waitcnt vmcnt(6)" ::: "memory");
    BARRIER();
    __builtin_amdgcn_s_setprio(1);
    cluster16<6>(acc, a00, a01, a10, a11, breg);
    __builtin_amdgcn_s_setprio(0);
    BARRIER();
  }
}

__global__ __launch_bounds__(512, 2) void gemm_lse8(
    const unsigned short* __restrict__ Xb, const unsigned short* __restrict__ Wb,
    float* __restrict__ pmax, float* __restrict__ psum) {
  extern __shared__ char lds[];
  const int tid = threadIdx.x;
  const int lane = tid & 63;
  const int wid = tid >> 6;
  const int wm = wid >> 2, wn = wid & 3;

  // XCD-aware swizzle (2000 % 8 == 0 -> bijective), mt-fastest for W reuse.
  int logical = (blockIdx.x & 7) * (CT2 * MT2 / 8) + (blockIdx.x >> 3);
  const int ct = logical / MT2, mt = logical - ct * MT2;
  const int mbase = mt * BM2, cbase = ct * BN2;

  const int g4 = (lane >> 4) << 4;
  const int sx = (lane & 7) << 4;          // row&7 == lane&7 for frag rows
  const int c0 = g4 ^ sx;                  // kk=0 column byte (swizzled)
  const int c1 = (64 + g4) ^ sx;           // kk=1
  const int aRowByte = ((wm << 7) + (lane & 15)) * 128;
  const int bRowByte = ((wn << 6) + (lane & 15)) * 128;

  f32x4 acc[8][4];
#pragma unroll
  for (int i = 0; i < 8; i++)
#pragma unroll
    for (int j = 0; j < 4; j++) { f32x4 z = {0.f, 0.f, 0.f, 0.f}; acc[i][j] = z; }

  // Prologue. Issue order: B(0)x4, A(0)ch0,ch2, A(0)ch1,ch3, B(1)x4;
  // vmcnt(6) -> outstanding = {A(0)ch13 x2, B(1) x4} = steady-state invariant.
  {
    char* b0 = lds + 32768;
    char* b1 = lds + 65536 + 32768;
    stage_chunk(Wb, cbase + 0,   0, b0 + 0,     tid);
    stage_chunk(Wb, cbase + 64,  0, b0 + 8192,  tid);
    stage_chunk(Wb, cbase + 128, 0, b0 + 16384, tid);
    stage_chunk(Wb, cbase + 192, 0, b0 + 24576, tid);
    stage_chunk(Xb, mbase + 0,   0, lds + 0,     tid);
    stage_chunk(Xb, mbase + 128, 0, lds + 16384, tid);
    stage_chunk(Xb, mbase + 64,  0, lds + 8192,  tid);
    stage_chunk(Xb, mbase + 192, 0, lds + 24576, tid);
    stage_chunk(Wb, cbase + 0,   1, b1 + 0,     tid);
    stage_chunk(Wb, cbase + 64,  1, b1 + 8192,  tid);
    stage_chunk(Wb, cbase + 128, 1, b1 + 16384, tid);
    stage_chunk(Wb, cbase + 192, 1, b1 + 24576, tid);
    asm volatile("s_waitcnt vmcnt(6)" ::: "memory");
    BARRIER();
  }

#pragma unroll 1
  for (int i = 0; i < NKT / 2; i++) {
    int g0 = 2 * i, g1 = 2 * i + 1;
    int b0t = (g0 + 2 < NKT) ? g0 + 2 : NKT - 1;
    int a1t = (g1 + 1 < NKT) ? g1 + 1 : NKT - 1;
    int b1t = (g1 + 2 < NKT) ? g1 + 2 : NKT - 1;
    phase_group<0>(lds, Xb, Wb, mbase, cbase, g0 + 1, b0t, tid,
                   aRowByte, bRowByte, c0, c1, acc);
    phase_group<1>(lds, Xb, Wb, mbase, cbase, a1t, b1t, tid,
                   aRowByte, bRowByte, c0, c1, acc);
  }

  asm volatile("s_waitcnt vmcnt(0)" ::: "memory");
  __syncthreads();

  // Per-row (max, sum-exp) over this block's 256 vocab columns.
  // 16x16 C/D map: col = lane&15, row = (lane>>4)*4 + q.
  float2* red = (float2*)lds;   // [256 rows][4 wn]
#pragma unroll
  for (int mf = 0; mf < 8; mf++) {
#pragma unroll
    for (int qq = 0; qq < 4; qq++) {
      float v0 = acc[mf][0][qq], v1 = acc[mf][1][qq];
      float v2 = acc[mf][2][qq], v3 = acc[mf][3][qq];
      float mx = fmaxf(fmaxf(v0, v1), fmaxf(v2, v3));
#pragma unroll
      for (int d = 1; d < 16; d <<= 1) mx = fmaxf(mx, __shfl_xor(mx, d));
      float se = __expf(v0 - mx) + __expf(v1 - mx) + __expf(v2 - mx) + __expf(v3 - mx);
#pragma unroll
      for (int d = 1; d < 16; d <<= 1) se += __shfl_xor(se, d);
      if ((lane & 15) == 0) {
        int row = (wm << 7) + mf * 16 + ((lane >> 4) << 2) + qq;
        float2 v; v.x = mx; v.y = se;
        red[row * 4 + wn] = v;
      }
    }
  }
  __syncthreads();
  if (tid < 256) {
    float M = -INFINITY, S = 0.f;
#pragma unroll
    for (int w = 0; w < 4; w++) {
      float2 rr = red[tid * 4 + w];
      float Mn = fmaxf(M, rr.x);
      S = S * __expf(M - Mn) + rr.y * __expf(rr.x - Mn);
      M = Mn;
    }
    size_t o = (size_t)ct * N_TOK + mbase + tid;
    pmax[o] = M;
    psum[o] = S;
  }
}

// ---------------- legacy 128^2 kernel, small-ws fallback (fp32 inputs) ------
__global__ __launch_bounds__(256) void gemm_lse_small(
    const float* __restrict__ Xf, const float* __restrict__ Wf,
    float* __restrict__ pmax, float* __restrict__ psum) {
  __shared__ unsigned short As[BM * BK];
  __shared__ unsigned short Bs[BN * BK];
  const int ct = blockIdx.x / MT_NUM;
  const int mt = blockIdx.x % MT_NUM;
  const int mbase = mt * BM, cbase = ct * BN;
  const int tid = threadIdx.x;
  const int lane = tid & 63;
  const int wid = tid >> 6;
  const int wr = wid >> 1, wc = wid & 1;
  f32x4 acc[4][4];
#pragma unroll
  for (int i = 0; i < 4; i++)
#pragma unroll
    for (int j = 0; j < 4; j++) { f32x4 z = {0.f, 0.f, 0.f, 0.f}; acc[i][j] = z; }
  for (int ks = 0; ks < H_DIM / BK; ks++) {
    const int k0 = ks * BK;
#pragma unroll
    for (int r = 0; r < 4; r++) {
      int o = r * 4096 + wid * 1024 + lane * 16;
      int row = o >> 7;
      int kc = (o & 127) >> 1;
      const float* xs = Xf + (size_t)(mbase + row) * H_DIM + k0 + kc;
      const float* wv = Wf + (size_t)(cbase + row) * H_DIM + k0 + kc;
      float4 x0 = *(const float4*)xs, x1 = *(const float4*)(xs + 4);
      float4 w0 = *(const float4*)wv, w1 = *(const float4*)(wv + 4);
      short8 xa, wa;
      xa[0] = f2bf(x0.x); xa[1] = f2bf(x0.y); xa[2] = f2bf(x0.z); xa[3] = f2bf(x0.w);
      xa[4] = f2bf(x1.x); xa[5] = f2bf(x1.y); xa[6] = f2bf(x1.z); xa[7] = f2bf(x1.w);
      wa[0] = f2bf(w0.x); wa[1] = f2bf(w0.y); wa[2] = f2bf(w0.z); wa[3] = f2bf(w0.w);
      wa[4] = f2bf(w1.x); wa[5] = f2bf(w1.y); wa[6] = f2bf(w1.z); wa[7] = f2bf(w1.w);
      *(short8*)((char*)As + o) = xa;
      *(short8*)((char*)Bs + o) = wa;
    }
    __syncthreads();
#pragma unroll
    for (int kk = 0; kk < 2; kk++) {
      short8 a[4], b[4];
#pragma unroll
      for (int m = 0; m < 4; m++)
        a[m] = *(const short8*)((const char*)As +
                (wr * 64 + m * 16 + (lane & 15)) * 128 + kk * 64 + (lane >> 4) * 16);
#pragma unroll
      for (int n = 0; n < 4; n++)
        b[n] = *(const short8*)((const char*)Bs +
                (wc * 64 + n * 16 + (lane & 15)) * 128 + kk * 64 + (lane >> 4) * 16);
#pragma unroll
      for (int m = 0; m < 4; m++)
#pragma unroll
        for (int n = 0; n < 4; n++)
          acc[m][n] = __builtin_amdgcn_mfma_f32_16x16x32_bf16(a[m], b[n], acc[m][n], 0, 0, 0);
    }
    __syncthreads();
  }
  float* red = (float*)As;
  const int g = lane >> 4;
#pragma unroll
  for (int m = 0; m < 4; m++) {
#pragma unroll
    for (int q = 0; q < 4; q++) {
      float v0 = acc[m][0][q], v1 = acc[m][1][q], v2 = acc[m][2][q], v3 = acc[m][3][q];
      float mx = fmaxf(fmaxf(v0, v1), fmaxf(v2, v3));
#pragma unroll
      for (int d = 1; d < 16; d <<= 1) mx = fmaxf(mx, __shfl_xor(mx, d));
      float se = __expf(v0 - mx) + __expf(v1 - mx) + __expf(v2 - mx) + __expf(v3 - mx);
#pragma unroll
      for (int d = 1; d < 16; d <<= 1) se += __shfl_xor(se, d);
      if ((lane & 15) == 0) {
        int row = wr * 64 + m * 16 + g * 4 + q;
        red[row * 4 + wc * 2 + 0] = mx;
        red[row * 4 + wc * 2 + 1] = se;
      }
    }
  }
  __syncthreads();
  if (tid < BM) {
    float m0 = red[tid * 4 + 0], s0 = red[tid * 4 + 1];
    float m1 = red[tid * 4 + 2], s1 = red[tid * 4 + 3];
    float M = fmaxf(m0, m1);
    float S = s0 * __expf(m0 - M) + s1 * __expf(m1 - M);
    size_t o = (size_t)ct * N_TOK + mbase + tid;
    pmax[o] = M;
    psum[o] = S;
  }
}

// ---------------- exact fp32 target logit + reduction kernels ---------------
__global__ __launch_bounds__(256) void target_logit(
    const float* __restrict__ X, const float* __restrict__ W,
    const int* __restrict__ y, float* __restrict__ tl) {
  __shared__ float red[4];
  int row = blockIdx.x;
  int lab = y[row];
  float s = 0.f;
  if (lab >= 0 && lab < V_DIM) {
    const float4* xr = (const float4*)(X + (size_t)row * H_DIM);
    const float4* wr = (const float4*)(W + (size_t)lab * H_DIM);
    for (int i = threadIdx.x; i < H_DIM / 4; i += 256) {
      float4 a = xr[i], b = wr[i];
      s += a.x * b.x + a.y * b.y + a.z * b.z + a.w * b.w;
    }
  }
#pragma unroll
  for (int o = 32; o > 0; o >>= 1) s += __shfl_down(s, o);
  if ((threadIdx.x & 63) == 0) red[threadIdx.x >> 6] = s;
  __syncthreads();
  if (threadIdx.x == 0) tl[row] = red[0] + red[1] + red[2] + red[3];
}

__global__ __launch_bounds__(256) void combine_rows(
    const float* __restrict__ pmax, const float* __restrict__ psum,
    const float* __restrict__ tl, const int* __restrict__ y,
    float* __restrict__ lossb, float* __restrict__ validb, int n_ct) {
  int row = blockIdx.x * 256 + threadIdx.x;
  if (row >= N_TOK) return;
  float M = -INFINITY, S = 0.f;
  for (int ct = 0; ct < n_ct; ct++) {
    float m = pmax[(size_t)ct * N_TOK + row];
    float s = psum[(size_t)ct * N_TOK + row];
    float Mn = fmaxf(M, m);
    S = S * __expf(M - Mn) + s * __expf(m - Mn);
    M = Mn;
  }
  bool valid = (y[row] != -100);
  lossb[row] = valid ? (M + __logf(S) - tl[row]) : 0.f;
  validb[row] = valid ? 1.f : 0.f;
}

__global__ __launch_bounds__(256) void finalize_loss(
    const float* __restrict__ lossb, const float* __restrict__ validb,
    float* __restrict__ out) {
  __shared__ float rs[4], rc[4];
  float s = 0.f, c = 0.f;
  for (int i = threadIdx.x; i < N_TOK; i += 256) { s += lossb[i]; c += validb[i]; }
#pragma unroll
  for (int o = 32; o > 0; o >>= 1) { s += __shfl_down(s, o); c += __shfl_down(c, o); }
  if ((threadIdx.x & 63) == 0) { rs[threadIdx.x >> 6] = s; rc[threadIdx.x >> 6] = c; }
  __syncthreads();
  if (threadIdx.x == 0) {
    float S = rs[0] + rs[1] + rs[2] + rs[3];
    float C = rc[0] + rc[1] + rc[2] + rc[3];
    out[0] = S / fmaxf(C, 1.f);
  }
}

extern "C" void kernel_launch(void* const* d_in, const int* in_sizes, int n_in,
                              void* d_out, int out_size, void* d_ws, size_t ws_size,
                              hipStream_t stream) {
  const float* x = (const float*)d_in[0];
  const int* y = (const int*)d_in[1];
  const float* W = (const float*)d_in[2];
  float* out = (float*)d_out;
  char* ws = (char*)d_ws;

  const size_t szWb = (size_t)V_DIM * H_DIM * 2;
  const size_t szXb = (size_t)N_TOK * H_DIM * 2;
  const size_t szP  = (size_t)CT_NUM * N_TOK * 4;   // sized for 250-tile fallback
  const size_t szT  = (size_t)N_TOK * 4;
  const size_t needFull = szWb + szXb + 2 * szP + 3 * szT;

  bool full = (ws_size >= needFull);
  unsigned short* Wb = nullptr;
  unsigned short* Xb = nullptr;
  size_t off = 0;
  if (full) { Wb = (unsigned short*)ws; Xb = (unsigned short*)(ws + szWb); off = szWb + szXb; }
  float* pmax   = (float*)(ws + off); off += szP;
  float* psum   = (float*)(ws + off); off += szP;
  float* tl     = (float*)(ws + off); off += szT;
  float* lossb  = (float*)(ws + off); off += szT;
  float* validb = (float*)(ws + off);

  if (full) {
    cast_f32_to_bf16<<<4096, 256, 0, stream>>>(W, Wb, (int)((size_t)V_DIM * H_DIM / 4));
    cast_f32_to_bf16<<<1024, 256, 0, stream>>>(x, Xb, (int)((size_t)N_TOK * H_DIM / 4));
    (void)hipFuncSetAttribute((const void*)gemm_lse8,
        hipFuncAttributeMaxDynamicSharedMemorySize, 131072);
    gemm_lse8<<<CT2 * MT2, 512, 131072, stream>>>(Xb, Wb, pmax, psum);
    target_logit<<<N_TOK, 256, 0, stream>>>(x, W, y, tl);
    combine_rows<<<N_TOK / 256, 256, 0, stream>>>(pmax, psum, tl, y, lossb, validb, CT2);
  } else {
    gemm_lse_small<<<CT_NUM * MT_NUM, 256, 0, stream>>>(x, W, pmax, psum);
    target_logit<<<N_TOK, 256, 0, stream>>>(x, W, y, tl);
    combine_rows<<<N_TOK / 256, 256, 0, stream>>>(pmax, psum, tl, y, lossb, validb, CT_NUM);
  }
  finalize_loss<<<1, 256, 0, stream>>>(lossb, validb, out);
}

// Round 6
// 938.950 us; speedup vs baseline: 1.4468x; 1.1930x over previous
//
#include <hip/hip_runtime.h>
#include <stdint.h>
#include <math.h>

#define N_TOK 4096
#define H_DIM 4096
#define V_DIM 32000

// ---- 8-phase 256x256 fp8 GEMM geometry ----
#define BM2 256
#define BN2 256
#define BK2 64
#define NKT (H_DIM / BK2)     // 64 K-tiles
#define CT2 (V_DIM / BN2)     // 125 column tiles
#define MT2 (N_TOK / BM2)     // 16 row tiles
#define WSCALE 16.0f          // W pre-scale (avoids e4m3 subnormals)
#define WSCALE_INV 0.0625f

// ---- legacy 128x128 fallback geometry (small-ws, fp32 inputs) ----
#define BM 128
#define BN 128
#define BK 64
#define CT_NUM (V_DIM / BN)   // 250
#define MT_NUM (N_TOK / BM)   // 32

typedef __attribute__((ext_vector_type(8))) short short8;
typedef __attribute__((ext_vector_type(4))) float f32x4;
typedef __attribute__((ext_vector_type(2))) long long2_t;

#define MFMA16(a, b, c) __builtin_amdgcn_mfma_f32_16x16x32_bf16(a, b, c, 0, 0, 0)
#define MFMAF8(a, b, c) __builtin_amdgcn_mfma_f32_16x16x32_fp8_fp8(a, b, c, 0, 0, 0)
#define BARRIER() asm volatile("s_barrier" ::: "memory")

__device__ __forceinline__ unsigned short f2bf(float x) {
  union { float f; unsigned int u; } v; v.f = x;
  unsigned int r = v.u + 0x7fffu + ((v.u >> 16) & 1u);
  return (unsigned short)(r >> 16);
}

__device__ __forceinline__ unsigned int pk4(float a, float b, float c, float d) {
  int v = __builtin_amdgcn_cvt_pk_fp8_f32(a, b, 0, false);
  v = __builtin_amdgcn_cvt_pk_fp8_f32(c, d, v, true);
  return (unsigned int)v;
}

__device__ __forceinline__ void async16(const void* g, void* lds) {
  __builtin_amdgcn_global_load_lds(
      (const __attribute__((address_space(1))) void*)g,
      (__attribute__((address_space(3))) void*)lds, 16, 0, 0);
}

// f32 -> fp8 e4m3 with kk-interleaved permutation per 64-element block:
// out[b*64 + s*16 + h*8 + e] = fp8(scale * in[b*64 + h*32 + s*8 + e]).
// A 16B out slot = [kk0-half 8B][kk1-half 8B] for one MFMA lane-group.
__global__ __launch_bounds__(256) void cast_f32_to_fp8_perm(
    const float* __restrict__ in, uint4* __restrict__ out, long nslots,
    float scale) {
  long stride = (long)gridDim.x * blockDim.x;
  for (long slot = (long)blockIdx.x * blockDim.x + threadIdx.x; slot < nslots;
       slot += stride) {
    long b = slot >> 2;
    int s = (int)(slot & 3);
    const float* p0 = in + b * 64 + s * 8;
    const float* p1 = p0 + 32;
    float4 a0 = *(const float4*)p0, a1 = *(const float4*)(p0 + 4);
    float4 c0 = *(const float4*)p1, c1 = *(const float4*)(p1 + 4);
    uint4 o;
    o.x = pk4(a0.x * scale, a0.y * scale, a0.z * scale, a0.w * scale);
    o.y = pk4(a1.x * scale, a1.y * scale, a1.z * scale, a1.w * scale);
    o.z = pk4(c0.x * scale, c0.y * scale, c0.z * scale, c0.w * scale);
    o.w = pk4(c1.x * scale, c1.y * scale, c1.z * scale, c1.w * scale);
    out[slot] = o;
  }
}

// Stage one 128-row x 64B fp8 chunk (8 KB), 512 threads, 1 DMA instr/wave.
// Thread -> dest (r = tid>>2, slot p = tid&3); source slot = p ^ (r&3)
// (XOR swizzle carried by the source address; LDS dest stays linear).
__device__ __forceinline__ void stage8(const uint8_t* __restrict__ src,
                                       int grow0, int kt, char* dest, int tid) {
  const int r = tid >> 2;
  const int p = tid & 3;
  const int s = p ^ (r & 3);
  const uint8_t* g = src + (size_t)(grow0 + r) * H_DIM + (size_t)kt * 64 + s * 16;
  async16(g, dest + (tid >> 6) * 1024);
}

// 16-MFMA cluster: m-frags MF,MF+1 x 4 n-frags x kk0/kk1 (dep distance 8).
template<int MF>
__device__ __forceinline__ void cluster16f8(f32x4 (&acc)[8][4],
    long2_t aL, long2_t aH, long2_t (&breg)[4]) {
#pragma unroll
  for (int nf = 0; nf < 4; nf++) acc[MF][nf]     = MFMAF8(aL[0], breg[nf][0], acc[MF][nf]);
#pragma unroll
  for (int nf = 0; nf < 4; nf++) acc[MF + 1][nf] = MFMAF8(aH[0], breg[nf][0], acc[MF + 1][nf]);
#pragma unroll
  for (int nf = 0; nf < 4; nf++) acc[MF][nf]     = MFMAF8(aL[1], breg[nf][1], acc[MF][nf]);
#pragma unroll
  for (int nf = 0; nf < 4; nf++) acc[MF + 1][nf] = MFMAF8(aH[1], breg[nf][1], acc[MF + 1][nf]);
}

// One K-tile g (4 phases), tile data in buf P = g&1 (32 KB/buf: A 16K, B 16K).
// Stages: q0/q1 -> A(g+1) halves into buf^1; q2/q3 -> B(g+2) halves into
// CURRENT buf's B region (B(g) was register-captured into breg at q0).
// vmcnt FIFO (1 instr/wave/stage): entering q0: [B(g+1)h0, B(g+1)h1].
//   q0 +A(g+1)h0 -> 3; q1 +h1 -> 4; q2 +B(g+2)h0 -> 5; q3 +h1 -> 6;
//   vmcnt(2) at q3 drains B(g+1) (read next q0) + A(g+1) (read next q0/q1),
//   leaves [B(g+2)x2] -> invariant. A h1 slack: 2 phases; B slack: 5 phases.
template<int P>
__device__ __forceinline__ void phase_tile(char* lds,
    const uint8_t* __restrict__ Xq, const uint8_t* __restrict__ Wq,
    int mbase, int cbase, int ktA, int ktB, int tid,
    const int (&aOff)[8], const int (&bOff)[4], f32x4 (&acc)[8][4]) {
  const char* aB = lds + P * 32768;
  const char* bB = aB + 16384;
  char* aN = lds + (P ^ 1) * 32768;
  char* bC = lds + P * 32768 + 16384;
  long2_t breg[4];

  // ---- q0: frags 0,1 (+ capture all B frags) ----
  stage8(Xq, mbase + 0, ktA, aN + 0, tid);
#pragma unroll
  for (int nf = 0; nf < 4; nf++) breg[nf] = *(const long2_t*)(bB + bOff[nf]);
  {
    long2_t a0 = *(const long2_t*)(aB + aOff[0]);
    long2_t a1 = *(const long2_t*)(aB + aOff[1]);
    BARRIER();
    __builtin_amdgcn_s_setprio(1);
    cluster16f8<0>(acc, a0, a1, breg);
    __builtin_amdgcn_s_setprio(0);
    BARRIER();
  }
  // ---- q1: frags 2,3 ----
  stage8(Xq, mbase + 128, ktA, aN + 8192, tid);
  {
    long2_t a0 = *(const long2_t*)(aB + aOff[2]);
    long2_t a1 = *(const long2_t*)(aB + aOff[3]);
    BARRIER();
    __builtin_amdgcn_s_setprio(1);
    cluster16f8<2>(acc, a0, a1, breg);
    __builtin_amdgcn_s_setprio(0);
    BARRIER();
  }
  // ---- q2: frags 4,5 ----
  stage8(Wq, cbase + 0, ktB, bC + 0, tid);
  {
    long2_t a0 = *(const long2_t*)(aB + aOff[4]);
    long2_t a1 = *(const long2_t*)(aB + aOff[5]);
    BARRIER();
    __builtin_amdgcn_s_setprio(1);
    cluster16f8<4>(acc, a0, a1, breg);
    __builtin_amdgcn_s_setprio(0);
    BARRIER();
  }
  // ---- q3: frags 6,7 ----
  stage8(Wq, cbase + 128, ktB, bC + 8192, tid);
  {
    long2_t a0 = *(const long2_t*)(aB + aOff[6]);
    long2_t a1 = *(const long2_t*)(aB + aOff[7]);
    asm volatile("s_waitcnt vmcnt(2)" ::: "memory");
    BARRIER();
    __builtin_amdgcn_s_setprio(1);
    cluster16f8<6>(acc, a0, a1, breg);
    __builtin_amdgcn_s_setprio(0);
    BARRIER();
  }
}

__global__ __launch_bounds__(512, 2) void gemm_lse8(
    const uint8_t* __restrict__ Xq, const uint8_t* __restrict__ Wq,
    float* __restrict__ pmax, float* __restrict__ psum) {
  extern __shared__ char lds[];
  const int tid = threadIdx.x;
  const int lane = tid & 63;
  const int wid = tid >> 6;
  const int wm = wid >> 2, wn = wid & 3;

  // XCD-aware swizzle (2000 % 8 == 0 -> bijective), mt-fastest for W reuse.
  int logical = (blockIdx.x & 7) * (CT2 * MT2 / 8) + (blockIdx.x >> 3);
  const int ct = logical / MT2, mt = logical - ct * MT2;
  const int mbase = mt * BM2, cbase = ct * BN2;

  // Fragment byte offsets. Rows are 64B; logical slot for lane-group g is
  // physical slot g ^ (row&3); row&3 == lane&3 for all frag rows.
  const int sl16 = (((lane >> 4) ^ (lane & 3)) << 4);
  int aOff[8], bOff[4];
#pragma unroll
  for (int mf = 0; mf < 8; mf++)
    aOff[mf] = (wm * 128 + mf * 16 + (lane & 15)) * 64 + sl16;
#pragma unroll
  for (int nf = 0; nf < 4; nf++)
    bOff[nf] = (wn * 64 + nf * 16 + (lane & 15)) * 64 + sl16;

  f32x4 acc[8][4];
#pragma unroll
  for (int i = 0; i < 8; i++)
#pragma unroll
    for (int j = 0; j < 4; j++) { f32x4 z = {0.f, 0.f, 0.f, 0.f}; acc[i][j] = z; }

  // Prologue: B(0), A(0) -> buf0; B(1) -> buf1. vmcnt(2) drains B(0)+A(0),
  // leaves [B(1)x2] = steady-state invariant.
  stage8(Wq, cbase + 0,   0, lds + 16384, tid);
  stage8(Wq, cbase + 128, 0, lds + 24576, tid);
  stage8(Xq, mbase + 0,   0, lds + 0,     tid);
  stage8(Xq, mbase + 128, 0, lds + 8192,  tid);
  stage8(Wq, cbase + 0,   1, lds + 49152, tid);
  stage8(Wq, cbase + 128, 1, lds + 57344, tid);
  asm volatile("s_waitcnt vmcnt(2)" ::: "memory");
  BARRIER();

#pragma unroll 1
  for (int i = 0; i < NKT / 2; i++) {
    int g0 = 2 * i, g1 = 2 * i + 1;
    int a0t = g0 + 1;                                   // <= 63 always
    int b0t = (g0 + 2 < NKT) ? g0 + 2 : NKT - 1;
    int a1t = (g1 + 1 < NKT) ? g1 + 1 : NKT - 1;
    int b1t = (g1 + 2 < NKT) ? g1 + 2 : NKT - 1;
    phase_tile<0>(lds, Xq, Wq, mbase, cbase, a0t, b0t, tid, aOff, bOff, acc);
    phase_tile<1>(lds, Xq, Wq, mbase, cbase, a1t, b1t, tid, aOff, bOff, acc);
  }

  asm volatile("s_waitcnt vmcnt(0)" ::: "memory");
  __syncthreads();

  // Per-row (max, sum-exp) over this block's 256 vocab columns.
  // 16x16 C/D map: col = lane&15, row = (lane>>4)*4 + q. Undo W pre-scale.
  float2* red = (float2*)lds;   // [256 rows][4 wn]
#pragma unroll
  for (int mf = 0; mf < 8; mf++) {
#pragma unroll
    for (int qq = 0; qq < 4; qq++) {
      float v0 = acc[mf][0][qq] * WSCALE_INV, v1 = acc[mf][1][qq] * WSCALE_INV;
      float v2 = acc[mf][2][qq] * WSCALE_INV, v3 = acc[mf][3][qq] * WSCALE_INV;
      float mx = fmaxf(fmaxf(v0, v1), fmaxf(v2, v3));
#pragma unroll
      for (int d = 1; d < 16; d <<= 1) mx = fmaxf(mx, __shfl_xor(mx, d));
      float se = __expf(v0 - mx) + __expf(v1 - mx) + __expf(v2 - mx) + __expf(v3 - mx);
#pragma unroll
      for (int d = 1; d < 16; d <<= 1) se += __shfl_xor(se, d);
      if ((lane & 15) == 0) {
        int row = (wm << 7) + mf * 16 + ((lane >> 4) << 2) + qq;
        float2 v; v.x = mx; v.y = se;
        red[row * 4 + wn] = v;
      }
    }
  }
  __syncthreads();
  if (tid < 256) {
    float M = -INFINITY, S = 0.f;
#pragma unroll
    for (int w = 0; w < 4; w++) {
      float2 rr = red[tid * 4 + w];
      float Mn = fmaxf(M, rr.x);
      S = S * __expf(M - Mn) + rr.y * __expf(rr.x - Mn);
      M = Mn;
    }
    size_t o = (size_t)ct * N_TOK + mbase + tid;
    pmax[o] = M;
    psum[o] = S;
  }
}

// ---------------- legacy 128^2 kernel, small-ws fallback (fp32 inputs) ------
__global__ __launch_bounds__(256) void gemm_lse_small(
    const float* __restrict__ Xf, const float* __restrict__ Wf,
    float* __restrict__ pmax, float* __restrict__ psum) {
  __shared__ unsigned short As[BM * BK];
  __shared__ unsigned short Bs[BN * BK];
  const int ct = blockIdx.x / MT_NUM;
  const int mt = blockIdx.x % MT_NUM;
  const int mbase = mt * BM, cbase = ct * BN;
  const int tid = threadIdx.x;
  const int lane = tid & 63;
  const int wid = tid >> 6;
  const int wr = wid >> 1, wc = wid & 1;
  f32x4 acc[4][4];
#pragma unroll
  for (int i = 0; i < 4; i++)
#pragma unroll
    for (int j = 0; j < 4; j++) { f32x4 z = {0.f, 0.f, 0.f, 0.f}; acc[i][j] = z; }
  for (int ks = 0; ks < H_DIM / BK; ks++) {
    const int k0 = ks * BK;
#pragma unroll
    for (int r = 0; r < 4; r++) {
      int o = r * 4096 + wid * 1024 + lane * 16;
      int row = o >> 7;
      int kc = (o & 127) >> 1;
      const float* xs = Xf + (size_t)(mbase + row) * H_DIM + k0 + kc;
      const float* wv = Wf + (size_t)(cbase + row) * H_DIM + k0 + kc;
      float4 x0 = *(const float4*)xs, x1 = *(const float4*)(xs + 4);
      float4 w0 = *(const float4*)wv, w1 = *(const float4*)(wv + 4);
      short8 xa, wa;
      xa[0] = f2bf(x0.x); xa[1] = f2bf(x0.y); xa[2] = f2bf(x0.z); xa[3] = f2bf(x0.w);
      xa[4] = f2bf(x1.x); xa[5] = f2bf(x1.y); xa[6] = f2bf(x1.z); xa[7] = f2bf(x1.w);
      wa[0] = f2bf(w0.x); wa[1] = f2bf(w0.y); wa[2] = f2bf(w0.z); wa[3] = f2bf(w0.w);
      wa[4] = f2bf(w1.x); wa[5] = f2bf(w1.y); wa[6] = f2bf(w1.z); wa[7] = f2bf(w1.w);
      *(short8*)((char*)As + o) = xa;
      *(short8*)((char*)Bs + o) = wa;
    }
    __syncthreads();
#pragma unroll
    for (int kk = 0; kk < 2; kk++) {
      short8 a[4], b[4];
#pragma unroll
      for (int m = 0; m < 4; m++)
        a[m] = *(const short8*)((const char*)As +
                (wr * 64 + m * 16 + (lane & 15)) * 128 + kk * 64 + (lane >> 4) * 16);
#pragma unroll
      for (int n = 0; n < 4; n++)
        b[n] = *(const short8*)((const char*)Bs +
                (wc * 64 + n * 16 + (lane & 15)) * 128 + kk * 64 + (lane >> 4) * 16);
#pragma unroll
      for (int m = 0; m < 4; m++)
#pragma unroll
        for (int n = 0; n < 4; n++)
          acc[m][n] = MFMA16(a[m], b[n], acc[m][n]);
    }
    __syncthreads();
  }
  float* red = (float*)As;
  const int g = lane >> 4;
#pragma unroll
  for (int m = 0; m < 4; m++) {
#pragma unroll
    for (int q = 0; q < 4; q++) {
      float v0 = acc[m][0][q], v1 = acc[m][1][q], v2 = acc[m][2][q], v3 = acc[m][3][q];
      float mx = fmaxf(fmaxf(v0, v1), fmaxf(v2, v3));
#pragma unroll
      for (int d = 1; d < 16; d <<= 1) mx = fmaxf(mx, __shfl_xor(mx, d));
      float se = __expf(v0 - mx) + __expf(v1 - mx) + __expf(v2 - mx) + __expf(v3 - mx);
#pragma unroll
      for (int d = 1; d < 16; d <<= 1) se += __shfl_xor(se, d);
      if ((lane & 15) == 0) {
        int row = wr * 64 + m * 16 + g * 4 + q;
        red[row * 4 + wc * 2 + 0] = mx;
        red[row * 4 + wc * 2 + 1] = se;
      }
    }
  }
  __syncthreads();
  if (tid < BM) {
    float m0 = red[tid * 4 + 0], s0 = red[tid * 4 + 1];
    float m1 = red[tid * 4 + 2], s1 = red[tid * 4 + 3];
    float M = fmaxf(m0, m1);
    float S = s0 * __expf(m0 - M) + s1 * __expf(m1 - M);
    size_t o = (size_t)ct * N_TOK + mbase + tid;
    pmax[o] = M;
    psum[o] = S;
  }
}

// ---------------- exact fp32 target logit + reduction kernels ---------------
__global__ __launch_bounds__(256) void target_logit(
    const float* __restrict__ X, const float* __restrict__ W,
    const int* __restrict__ y, float* __restrict__ tl) {
  __shared__ float red[4];
  int row = blockIdx.x;
  int lab = y[row];
  float s = 0.f;
  if (lab >= 0 && lab < V_DIM) {
    const float4* xr = (const float4*)(X + (size_t)row * H_DIM);
    const float4* wr = (const float4*)(W + (size_t)lab * H_DIM);
    for (int i = threadIdx.x; i < H_DIM / 4; i += 256) {
      float4 a = xr[i], b = wr[i];
      s += a.x * b.x + a.y * b.y + a.z * b.z + a.w * b.w;
    }
  }
#pragma unroll
  for (int o = 32; o > 0; o >>= 1) s += __shfl_down(s, o);
  if ((threadIdx.x & 63) == 0) red[threadIdx.x >> 6] = s;
  __syncthreads();
  if (threadIdx.x == 0) tl[row] = red[0] + red[1] + red[2] + red[3];
}

__global__ __launch_bounds__(256) void combine_rows(
    const float* __restrict__ pmax, const float* __restrict__ psum,
    const float* __restrict__ tl, const int* __restrict__ y,
    float* __restrict__ lossb, float* __restrict__ validb, int n_ct) {
  int row = blockIdx.x * 256 + threadIdx.x;
  if (row >= N_TOK) return;
  float M = -INFINITY, S = 0.f;
  for (int ct = 0; ct < n_ct; ct++) {
    float m = pmax[(size_t)ct * N_TOK + row];
    float s = psum[(size_t)ct * N_TOK + row];
    float Mn = fmaxf(M, m);
    S = S * __expf(M - Mn) + s * __expf(m - Mn);
    M = Mn;
  }
  bool valid = (y[row] != -100);
  lossb[row] = valid ? (M + __logf(S) - tl[row]) : 0.f;
  validb[row] = valid ? 1.f : 0.f;
}

__global__ __launch_bounds__(256) void finalize_loss(
    const float* __restrict__ lossb, const float* __restrict__ validb,
    float* __restrict__ out) {
  __shared__ float rs[4], rc[4];
  float s = 0.f, c = 0.f;
  for (int i = threadIdx.x; i < N_TOK; i += 256) { s += lossb[i]; c += validb[i]; }
#pragma unroll
  for (int o = 32; o > 0; o >>= 1) { s += __shfl_down(s, o); c += __shfl_down(c, o); }
  if ((threadIdx.x & 63) == 0) { rs[threadIdx.x >> 6] = s; rc[threadIdx.x >> 6] = c; }
  __syncthreads();
  if (threadIdx.x == 0) {
    float S = rs[0] + rs[1] + rs[2] + rs[3];
    float C = rc[0] + rc[1] + rc[2] + rc[3];
    out[0] = S / fmaxf(C, 1.f);
  }
}

extern "C" void kernel_launch(void* const* d_in, const int* in_sizes, int n_in,
                              void* d_out, int out_size, void* d_ws, size_t ws_size,
                              hipStream_t stream) {
  const float* x = (const float*)d_in[0];
  const int* y = (const int*)d_in[1];
  const float* W = (const float*)d_in[2];
  float* out = (float*)d_out;
  char* ws = (char*)d_ws;

  const size_t szWq = (size_t)V_DIM * H_DIM;        // 131,072,000 (fp8)
  const size_t szXq = (size_t)N_TOK * H_DIM;        //  16,777,216 (fp8)
  const size_t szP  = (size_t)CT_NUM * N_TOK * 4;   // sized for 250-tile fallback
  const size_t szT  = (size_t)N_TOK * 4;
  const size_t needFull = szWq + szXq + 2 * szP + 3 * szT;

  bool full = (ws_size >= needFull);
  uint8_t* Wq = nullptr;
  uint8_t* Xq = nullptr;
  size_t off = 0;
  if (full) { Wq = (uint8_t*)ws; Xq = (uint8_t*)(ws + szWq); off = szWq + szXq; }
  float* pmax   = (float*)(ws + off); off += szP;
  float* psum   = (float*)(ws + off); off += szP;
  float* tl     = (float*)(ws + off); off += szT;
  float* lossb  = (float*)(ws + off); off += szT;
  float* validb = (float*)(ws + off);

  if (full) {
    cast_f32_to_fp8_perm<<<8192, 256, 0, stream>>>(
        W, (uint4*)Wq, (long)(szWq / 16), WSCALE);
    cast_f32_to_fp8_perm<<<2048, 256, 0, stream>>>(
        x, (uint4*)Xq, (long)(szXq / 16), 1.0f);
    (void)hipFuncSetAttribute((const void*)gemm_lse8,
        hipFuncAttributeMaxDynamicSharedMemorySize, 65536);
    gemm_lse8<<<CT2 * MT2, 512, 65536, stream>>>(Xq, Wq, pmax, psum);
    target_logit<<<N_TOK, 256, 0, stream>>>(x, W, y, tl);
    combine_rows<<<N_TOK / 256, 256, 0, stream>>>(pmax, psum, tl, y, lossb, validb, CT2);
  } else {
    gemm_lse_small<<<CT_NUM * MT_NUM, 256, 0, stream>>>(x, W, pmax, psum);
    target_logit<<<N_TOK, 256, 0, stream>>>(x, W, y, tl);
    combine_rows<<<N_TOK / 256, 256, 0, stream>>>(pmax, psum, tl, y, lossb, validb, CT_NUM);
  }
  finalize_loss<<<1, 256, 0, stream>>>(lossb, validb, out);
}